// Round 8
// baseline (413.057 us; speedup 1.0000x reference)
//
#include <hip/hip_runtime.h>
#include <math.h>

// Problem constants (fixed by the reference).
constexpr int kN  = 250000;
constexpr int kC  = 32;
constexpr int kFC = 16;
constexpr int kFN = 16;
constexpr int kV  = 64;

// ---------------------------------------------------------------------------
// Log-space fast path (transposed log-table + quadratic Gaussian form) with
// register-resident per-class scores, plus CANDIDATE-ONLY exact fallback.
//
//   acc[c] = K2_c + sum_f Lq[f][idx_f][c] + sum_f (alpha_cf*x_f^2 + beta_cf*x_f)
//
// ROUND-8 FIX: `float acc[32]` was never register-promoted (SROA failure on
// the alloca) -> every Gaussian f-iteration round-tripped 128 B/lane through
// scratch: WRITE_SIZE 491 MB, VALUBusy 6%, VGPR 64. Accumulators are now
// EIGHT float4 VARIABLES (a0..a7) touched only via static .x/.y/.z/.w member
// accesses -> guaranteed registers. AB is re-laid-out per-f as
// [32 alphas][32 betas] so coefficients load as uniform float4s.
// Arithmetic per class is unchanged (same values, same order -> same bits as
// the round-6/7 validated numerics).
//
// Accept iff best >= -86 AND top-2 gap >= 6e-3. Fallback exact-scores only
// candidate classes (bitmask); deep underflow (best < -86) -> all classes
// exact, preserving denormal / all-zero-tie -> first-max reference semantics.
// ---------------------------------------------------------------------------

// d_ws float layout:
constexpr int WS_LQ = 0;                     // [16][64][32] at [((f*64+v)<<5)+c]
constexpr int WS_AB = kFC * kV * kC;         // 32768: [16][64]: f-major,
                                             //   [f][0..31]=alpha_c, [f][32..63]=beta_c
constexpr int WS_K2 = WS_AB + kFN * 2 * kC;  // 33792: [32] K2_c
// total 33824 floats = 135,296 bytes

__global__ __launch_bounds__(256) void nbc_prep(
    const float* __restrict__ class_probs,
    const float* __restrict__ cat_probs,
    const float* __restrict__ means,
    const float* __restrict__ stds,
    float* __restrict__ ws)
{
    const float two_pi = 2.0f * (float)M_PI;
    const int b = blockIdx.x;
    if (b < 128) {
        // Transposed log-table: one element per thread.
        const int gid = b * 256 + threadIdx.x;        // 0 .. 32767
        const int c = gid >> 10;
        const int f = (gid >> 6) & 15;
        const int v = gid & 63;
        ws[WS_LQ + (((f << 6) + v) << 5) + c] = logf(cat_probs[gid]);
    } else {
        const int t = threadIdx.x;
        // ALL 512 {alpha,beta} pairs (strided loop; 512 > blockDim).
        for (int i = t; i < kC * kFN; i += 256) {
            const int c = i >> 4, f = i & 15;
            const float m  = means[c * kFN + f];
            const float s  = stds [c * kFN + f];
            const float rs = 1.0f / s;
            ws[WS_AB + f * 64 + c]      = -0.5f * (rs * rs);   // alpha
            ws[WS_AB + f * 64 + 32 + c] = (rs * rs) * m;       // beta
        }
        if (t < kC) {
            float k = logf(class_probs[t]);
            for (int f = 0; f < kFN; ++f) {
                const float m  = means[t * kFN + f];
                const float s  = stds [t * kFN + f];
                const float rs = 1.0f / s;
                k += logf(1.0f / (two_pi * (s * s))) + (-0.5f * (rs * rs)) * (m * m);
            }
            ws[WS_K2 + t] = k;
        }
    }
}

__global__ __launch_bounds__(256, 4) void nbc_main(
    const int*   __restrict__ X_cat,
    const float* __restrict__ X_num,
    const float* __restrict__ class_probs,
    const float* __restrict__ cat_probs,
    const float* __restrict__ means,
    const float* __restrict__ stds,
    const float* __restrict__ ws,
    int* __restrict__ out)
{
    const int n = blockIdx.x * 256 + threadIdx.x;
    if (n >= kN) return;

    // Vector-load the 16 categorical indices and 16 numeric features.
    int   idx[kFC];
    float x  [kFN];
    {
        const int4* p4 = reinterpret_cast<const int4*>(X_cat + (size_t)n * kFC);
        int4 a0 = p4[0], a1 = p4[1], a2 = p4[2], a3 = p4[3];
        idx[0]=a0.x;  idx[1]=a0.y;  idx[2]=a0.z;  idx[3]=a0.w;
        idx[4]=a1.x;  idx[5]=a1.y;  idx[6]=a1.z;  idx[7]=a1.w;
        idx[8]=a2.x;  idx[9]=a2.y;  idx[10]=a2.z; idx[11]=a2.w;
        idx[12]=a3.x; idx[13]=a3.y; idx[14]=a3.z; idx[15]=a3.w;

        const float4* q4 = reinterpret_cast<const float4*>(X_num + (size_t)n * kFN);
        float4 b0 = q4[0], b1 = q4[1], b2 = q4[2], b3 = q4[3];
        x[0]=b0.x;  x[1]=b0.y;  x[2]=b0.z;  x[3]=b0.w;
        x[4]=b1.x;  x[5]=b1.y;  x[6]=b1.z;  x[7]=b1.w;
        x[8]=b2.x;  x[9]=b2.y;  x[10]=b2.z; x[11]=b2.w;
        x[12]=b3.x; x[13]=b3.y; x[14]=b3.z; x[15]=b3.w;
    }

    const float*  __restrict__ Lq  = ws + WS_LQ;
    const float4* __restrict__ AB4 = reinterpret_cast<const float4*>(ws + WS_AB);
    const float4* __restrict__ K4  = reinterpret_cast<const float4*>(ws + WS_K2);

    // ---- fast path: 32 class scores in 8 float4 REGISTER variables ----
    float4 a0 = K4[0], a1 = K4[1], a2 = K4[2], a3 = K4[3];
    float4 a4 = K4[4], a5 = K4[5], a6 = K4[6], a7 = K4[7];

    // Categorical log-sums: per feature, 8 contiguous float4 covering all 32
    // classes (row is 128B-aligned). 128 independent 16B loads total.
#define CAT_ADD(A, J) { float4 v = r[J]; A.x += v.x; A.y += v.y; A.z += v.z; A.w += v.w; }
    #pragma unroll
    for (int f = 0; f < kFC; ++f) {
        const float4* __restrict__ r =
            reinterpret_cast<const float4*>(Lq + (((f << 6) + idx[f]) << 5));
        CAT_ADD(a0, 0) CAT_ADD(a1, 1) CAT_ADD(a2, 2) CAT_ADD(a3, 3)
        CAT_ADD(a4, 4) CAT_ADD(a5, 5) CAT_ADD(a6, 6) CAT_ADD(a7, 7)
    }
#undef CAT_ADD

    // Gaussian quadratic form: same fmaf(al, x^2, fmaf(be, x, acc)) as the
    // validated rounds; coefficients are wave-uniform float4 loads.
#define GAUSS(A, J) { float4 al = AB4[base + (J)]; float4 be = AB4[base + 8 + (J)]; \
        A.x = fmaf(al.x, xf2, fmaf(be.x, xf, A.x)); \
        A.y = fmaf(al.y, xf2, fmaf(be.y, xf, A.y)); \
        A.z = fmaf(al.z, xf2, fmaf(be.z, xf, A.z)); \
        A.w = fmaf(al.w, xf2, fmaf(be.w, xf, A.w)); }
    #pragma unroll
    for (int f = 0; f < kFN; ++f) {
        const float xf  = x[f];
        const float xf2 = xf * xf;
        const int base  = f * 16;             // float4 units: 8 alpha4 + 8 beta4
        GAUSS(a0, 0) GAUSS(a1, 1) GAUSS(a2, 2) GAUSS(a3, 3)
        GAUSS(a4, 4) GAUSS(a5, 5) GAUSS(a6, 6) GAUSS(a7, 7)
    }
#undef GAUSS

    // Top-2 tracking (first-max on exact equality via strict >).
    float best = -INFINITY, second = -INFINITY;
    int   besti = 0;
#define TOP2(T, C) { float t_ = (T); \
        if (t_ > best) { second = best; best = t_; besti = (C); } \
        else if (t_ > second) { second = t_; } }
#define SCAN4(A, B) TOP2(A.x, B) TOP2(A.y, (B)+1) TOP2(A.z, (B)+2) TOP2(A.w, (B)+3)
    SCAN4(a0, 0)  SCAN4(a1, 4)  SCAN4(a2, 8)  SCAN4(a3, 12)
    SCAN4(a4, 16) SCAN4(a5, 20) SCAN4(a6, 24) SCAN4(a7, 28)
#undef SCAN4
#undef TOP2

    if (best >= -86.0f && (best - second) >= 6.0e-3f) {
        out[n] = besti;
        return;
    }

    // Candidate bitmask — static component accesses only.
    const float thr = (best >= -86.0f) ? (best - 1.2e-2f) : -INFINITY;
    unsigned int mask = 0u;
#define MASK4(A, B) mask |= ((A.x >= thr) ? (1u << (B))     : 0u) \
                        |  ((A.y >= thr) ? (1u << ((B)+1)) : 0u) \
                        |  ((A.z >= thr) ? (1u << ((B)+2)) : 0u) \
                        |  ((A.w >= thr) ? (1u << ((B)+3)) : 0u);
    MASK4(a0, 0)  MASK4(a1, 4)  MASK4(a2, 8)  MASK4(a3, 12)
    MASK4(a4, 16) MASK4(a5, 20) MASK4(a6, 24) MASK4(a7, 28)
#undef MASK4

    // ---- fallback: exact scoring of candidate classes only ----
    const float two_pi = 2.0f * (float)M_PI;
    float bb = -INFINITY;
    int   bi = 0;

    #pragma unroll 1
    for (int c = 0; c < kC; ++c) {
        if ((mask >> c) & 1u) {
            // Bit-exact categorical product (reference order, ascending f).
            const float* __restrict__ row = cat_probs + (size_t)c * (kFC * kV);
            float cat = row[idx[0]];
            #pragma unroll
            for (int f = 1; f < kFC; ++f) {
                cat *= row[(f << 6) + idx[f]];
            }
            // Exact reference numerics (round-1 validated, bit-identical).
            float num;
            #pragma unroll
            for (int f = 0; f < kFN; ++f) {
                float m = means[c * kFN + f];
                float s = stds [c * kFN + f];
                float inv = 1.0f / (two_pi * (s * s));
                float z = (x[f] - m) / s;              // IEEE divide
                float e = expf(-0.5f * (z * z));
                float lik = inv * e;
                num = (f == 0) ? lik : num * lik;
            }
            float pred = (class_probs[c] * cat) * num; // ((cp*cat)*num) like ref
            if (pred > bb) { bb = pred; bi = c; }      // strict > -> first max
        }
    }
    out[n] = bi;
}

extern "C" void kernel_launch(void* const* d_in, const int* in_sizes, int n_in,
                              void* d_out, int out_size, void* d_ws, size_t ws_size,
                              hipStream_t stream) {
    const int*   X_cat       = (const int*)  d_in[0];
    const float* X_num       = (const float*)d_in[1];
    const float* class_probs = (const float*)d_in[2];
    const float* cat_probs   = (const float*)d_in[3];
    const float* means       = (const float*)d_in[4];
    const float* stds        = (const float*)d_in[5];
    int*   out = (int*)d_out;
    float* ws  = (float*)d_ws;   // 135,296 bytes used

    // 128 blocks build the transposed log-table; block 128 builds params.
    hipLaunchKernelGGL(nbc_prep, dim3(129), dim3(256), 0, stream,
                       class_probs, cat_probs, means, stds, ws);

    dim3 block(256);
    dim3 grid((kN + 255) / 256);
    hipLaunchKernelGGL(nbc_main, grid, block, 0, stream,
                       X_cat, X_num, class_probs, cat_probs, means, stds, ws, out);
}

// Round 9
// 184.335 us; speedup vs baseline: 2.2408x; 2.2408x over previous
//
#include <hip/hip_runtime.h>
#include <math.h>

// Problem constants (fixed by the reference).
constexpr int kN  = 250000;
constexpr int kC  = 32;
constexpr int kFC = 16;
constexpr int kFN = 16;
constexpr int kV  = 64;

// ---------------------------------------------------------------------------
// Log-space fast path + candidate-only exact fallback.
//
//   T_c = K2_c + sum_f Lq[f][idx_f][c] + sum_f (alpha_cf*x_f^2 + beta_cf*x_f)
// Lq[f][v][c] = logf(cat_probs[c][f][v]) (128 KB transposed table in d_ws),
// alpha=-0.5/s^2, beta=m/s^2, K2_c = logf(cp_c)+sum_f[logf(1/(2pi s^2))+alpha m^2].
// |T_c - log(S_exact_c)| <= ~3e-3 near the top. Accept iff best >= -86 AND
// top-2 gap >= 6e-3. Else fallback: recompute T_c per class; exact-score
// (reference op order, round-1-validated) classes with T_c >= best-1.2e-2
// (winner provably passes: both estimates within 3e-3 -> 6e-3 < 1.2e-2).
// Deep underflow (best < -86): thr=-inf -> all classes exact (denormal /
// all-zero-tie -> first-max reference semantics).
//
// ROUND-9 FIX (the scratch saga): rounds 6-8 all showed ~2 KB/thread scratch
// round-trip (WRITE_SIZE ~0.5 GB = 512 floats/sample) regardless of whether
// the 32 accumulators were an array or 8 named float4s -> the pathology is
// the fully-unrolled 32-class x 16-feature block (128 clustered gathers +
// 32-wide accumulate) spilled by the scheduler. Now classes are processed in
// 8 GROUPS OF 4 under a ROLLED loop: live state is ONE float4 accumulator +
// 16 precomputed row offsets; max in-flight gather results = 16 float4.
// No 32-wide state exists anywhere in the kernel.
// ---------------------------------------------------------------------------

// d_ws float layout:
constexpr int WS_LQ = 0;                     // [16][64][32] at [((f*64+v)<<5)+c]
constexpr int WS_AB = kFC * kV * kC;         // 32768: [16][64]: f-major,
                                             //   [f][0..31]=alpha_c, [f][32..63]=beta_c
constexpr int WS_K2 = WS_AB + kFN * 2 * kC;  // 33792: [32] K2_c
// total 33824 floats = 135,296 bytes

__global__ __launch_bounds__(256) void nbc_prep(
    const float* __restrict__ class_probs,
    const float* __restrict__ cat_probs,
    const float* __restrict__ means,
    const float* __restrict__ stds,
    float* __restrict__ ws)
{
    const float two_pi = 2.0f * (float)M_PI;
    const int b = blockIdx.x;
    if (b < 128) {
        // Transposed log-table: one element per thread.
        const int gid = b * 256 + threadIdx.x;        // 0 .. 32767
        const int c = gid >> 10;
        const int f = (gid >> 6) & 15;
        const int v = gid & 63;
        ws[WS_LQ + (((f << 6) + v) << 5) + c] = logf(cat_probs[gid]);
    } else {
        const int t = threadIdx.x;
        // ALL 512 {alpha,beta} pairs (strided loop; 512 > blockDim).
        for (int i = t; i < kC * kFN; i += 256) {
            const int c = i >> 4, f = i & 15;
            const float m  = means[c * kFN + f];
            const float s  = stds [c * kFN + f];
            const float rs = 1.0f / s;
            ws[WS_AB + f * 64 + c]      = -0.5f * (rs * rs);   // alpha
            ws[WS_AB + f * 64 + 32 + c] = (rs * rs) * m;       // beta
        }
        if (t < kC) {
            float k = logf(class_probs[t]);
            for (int f = 0; f < kFN; ++f) {
                const float m  = means[t * kFN + f];
                const float s  = stds [t * kFN + f];
                const float rs = 1.0f / s;
                k += logf(1.0f / (two_pi * (s * s))) + (-0.5f * (rs * rs)) * (m * m);
            }
            ws[WS_K2 + t] = k;
        }
    }
}

__global__ __launch_bounds__(256, 4) void nbc_main(
    const int*   __restrict__ X_cat,
    const float* __restrict__ X_num,
    const float* __restrict__ class_probs,
    const float* __restrict__ cat_probs,
    const float* __restrict__ means,
    const float* __restrict__ stds,
    const float* __restrict__ ws,
    int* __restrict__ out)
{
    const int n = blockIdx.x * 256 + threadIdx.x;
    if (n >= kN) return;

    // Vector-load the 16 categorical indices and 16 numeric features.
    int   idx[kFC];
    float x  [kFN];
    {
        const int4* p4 = reinterpret_cast<const int4*>(X_cat + (size_t)n * kFC);
        int4 a0 = p4[0], a1 = p4[1], a2 = p4[2], a3 = p4[3];
        idx[0]=a0.x;  idx[1]=a0.y;  idx[2]=a0.z;  idx[3]=a0.w;
        idx[4]=a1.x;  idx[5]=a1.y;  idx[6]=a1.z;  idx[7]=a1.w;
        idx[8]=a2.x;  idx[9]=a2.y;  idx[10]=a2.z; idx[11]=a2.w;
        idx[12]=a3.x; idx[13]=a3.y; idx[14]=a3.z; idx[15]=a3.w;

        const float4* q4 = reinterpret_cast<const float4*>(X_num + (size_t)n * kFN);
        float4 b0 = q4[0], b1 = q4[1], b2 = q4[2], b3 = q4[3];
        x[0]=b0.x;  x[1]=b0.y;  x[2]=b0.z;  x[3]=b0.w;
        x[4]=b1.x;  x[5]=b1.y;  x[6]=b1.z;  x[7]=b1.w;
        x[8]=b2.x;  x[9]=b2.y;  x[10]=b2.z; x[11]=b2.w;
        x[12]=b3.x; x[13]=b3.y; x[14]=b3.z; x[15]=b3.w;
    }

    // Per-sample Lq row offsets (float-element units). Static accesses only.
    int o[kFC];
    #pragma unroll
    for (int f = 0; f < kFC; ++f) o[f] = ((f << 6) + idx[f]) << 5;

    const float*  __restrict__ Lq  = ws + WS_LQ;
    const float4* __restrict__ AB4 = reinterpret_cast<const float4*>(ws + WS_AB);
    const float4* __restrict__ K4  = reinterpret_cast<const float4*>(ws + WS_K2);
    const float*  __restrict__ ABs = ws + WS_AB;
    const float*  __restrict__ K2  = ws + WS_K2;

    // ---- fast path: 8 rolled groups of 4 classes; one float4 acc live ----
    float best = -INFINITY, second = -INFINITY;
    int   besti = 0;

    #pragma unroll 1
    for (int g = 0; g < kC / 4; ++g) {
        float4 acc = K4[g];

        // Gaussian quadratic form (uniform coefficient loads).
        #pragma unroll
        for (int f = 0; f < kFN; ++f) {
            const float xf  = x[f];
            const float xf2 = xf * xf;
            float4 al = AB4[f * 16 + g];        // alphas, classes 4g..4g+3
            float4 be = AB4[f * 16 + 8 + g];    // betas
            acc.x = fmaf(al.x, xf2, fmaf(be.x, xf, acc.x));
            acc.y = fmaf(al.y, xf2, fmaf(be.y, xf, acc.y));
            acc.z = fmaf(al.z, xf2, fmaf(be.z, xf, acc.z));
            acc.w = fmaf(al.w, xf2, fmaf(be.w, xf, acc.w));
        }

        // Categorical log-sums: 16 float4 gathers (one per feature).
        #pragma unroll
        for (int f = 0; f < kFC; ++f) {
            float4 v = *reinterpret_cast<const float4*>(Lq + o[f] + (g << 2));
            acc.x += v.x;
            acc.y += v.y;
            acc.z += v.z;
            acc.w += v.w;
        }

        // Top-2 tracking (first-max on exact equality via strict >).
        const int c0 = g << 2;
#define TOP2(T, C) { float t_ = (T); \
        if (t_ > best) { second = best; best = t_; besti = (C); } \
        else if (t_ > second) { second = t_; } }
        TOP2(acc.x, c0) TOP2(acc.y, c0 + 1) TOP2(acc.z, c0 + 2) TOP2(acc.w, c0 + 3)
#undef TOP2
    }

    if (best >= -86.0f && (best - second) >= 6.0e-3f) {
        out[n] = besti;
        return;
    }

    // ---- fallback: recompute T_c per class; exact-score candidates ----
    const float thr    = (best >= -86.0f) ? (best - 1.2e-2f) : -INFINITY;
    const float two_pi = 2.0f * (float)M_PI;
    float bb = -INFINITY;
    int   bi = 0;

    #pragma unroll 1
    for (int c = 0; c < kC; ++c) {
        // T_c estimate (scalar; same +/-3e-3 bound as the fast path).
        float t = K2[c];
        #pragma unroll
        for (int f = 0; f < kFC; ++f) t += Lq[o[f] + c];
        #pragma unroll
        for (int f = 0; f < kFN; ++f) {
            const float xf = x[f];
            float al = ABs[f * 64 + c];
            float be = ABs[f * 64 + 32 + c];
            t = fmaf(al, xf * xf, fmaf(be, xf, t));
        }

        if (t >= thr) {
            // Bit-exact categorical product (reference order, ascending f).
            const float* __restrict__ row = cat_probs + (size_t)c * (kFC * kV);
            float cat = row[idx[0]];
            #pragma unroll
            for (int f = 1; f < kFC; ++f) {
                cat *= row[(f << 6) + idx[f]];
            }
            // Exact reference numerics (round-1 validated, bit-identical).
            float num;
            #pragma unroll
            for (int f = 0; f < kFN; ++f) {
                float m = means[c * kFN + f];
                float s = stds [c * kFN + f];
                float inv = 1.0f / (two_pi * (s * s));
                float z = (x[f] - m) / s;              // IEEE divide
                float e = expf(-0.5f * (z * z));
                float lik = inv * e;
                num = (f == 0) ? lik : num * lik;
            }
            float pred = (class_probs[c] * cat) * num; // ((cp*cat)*num) like ref
            if (pred > bb) { bb = pred; bi = c; }      // strict > -> first max
        }
    }
    out[n] = bi;
}

extern "C" void kernel_launch(void* const* d_in, const int* in_sizes, int n_in,
                              void* d_out, int out_size, void* d_ws, size_t ws_size,
                              hipStream_t stream) {
    const int*   X_cat       = (const int*)  d_in[0];
    const float* X_num       = (const float*)d_in[1];
    const float* class_probs = (const float*)d_in[2];
    const float* cat_probs   = (const float*)d_in[3];
    const float* means       = (const float*)d_in[4];
    const float* stds        = (const float*)d_in[5];
    int*   out = (int*)d_out;
    float* ws  = (float*)d_ws;   // 135,296 bytes used

    // 128 blocks build the transposed log-table; block 128 builds params.
    hipLaunchKernelGGL(nbc_prep, dim3(129), dim3(256), 0, stream,
                       class_probs, cat_probs, means, stds, ws);

    dim3 block(256);
    dim3 grid((kN + 255) / 256);
    hipLaunchKernelGGL(nbc_main, grid, block, 0, stream,
                       X_cat, X_num, class_probs, cat_probs, means, stds, ws, out);
}